// Round 11
// baseline (142.286 us; speedup 1.0000x reference)
//
#include <hip/hip_runtime.h>
#include <math.h>

// B=65536 rows, N=1024 cols, fp32.
//   t_b = argmax_c target[b,c]  (first-max tie-break)
//   out = mean_b(-log(y[b,t_b]+1e-8)) + sum_{b,c} w[popc(t_b^c)]*y[b,c]/(B*N), w[p]=(p==0)?0:6^p
// R3-R10 evidence: R4 structure (2-row interleave, VGPR 60, no spill) = 99.6us champion.
// Every deviation regressed: >16 live float4 -> spill (R5/R6) or LDS-promote (R8/R10);
// kernel split -> +20us (R7). R11 = R4 body exactly (plain launch_bounds(256), named
// scalars) + atomic finish to drop the 2nd launch. If clean -> practical roofline.

#define B_ROWS 65536
#define N_COLS 1024
#define WAVES_PER_BLOCK 4
#define ROWS_BLOCKS 2048
#define ROWS_THREADS (WAVES_PER_BLOCK * 64)
#define NWAVES (ROWS_BLOCKS * WAVES_PER_BLOCK)  // 8192 waves; 8 rows/wave = 4 iters x 2 rows

__global__ __launch_bounds__(ROWS_THREADS)
void ce_rows_kernel(const float* __restrict__ y_true,
                    const float* __restrict__ target,
                    float* __restrict__ out) {
    __shared__ float w_lds[16];
    __shared__ float wave_part[WAVES_PER_BLOCK];

    const int tid = threadIdx.x;
    if (tid < 16) {
        float w = 1.0f;
        for (int p = 0; p < tid; ++p) w *= 6.0f;   // exact: 6^10 < 2^26
        w_lds[tid] = (tid == 0) ? 0.0f : w;
    }
    __syncthreads();

    const int lane  = tid & 63;
    const int wid   = tid >> 6;
    const int gwave = blockIdx.x * WAVES_PER_BLOCK + wid;

    float acc_pt = 0.0f;   // lane-private weighted-sum partial
    float acc_lg = 0.0f;   // lane-private sum of log(y[t]+1e-8), owner lanes only

    #pragma unroll 1
    for (int it = 0; it < 4; ++it) {
        const int rowA = gwave + (2 * it)     * NWAVES;
        const int rowB = gwave + (2 * it + 1) * NWAVES;
        const float4* tA = (const float4*)(target + (size_t)rowA * N_COLS);
        const float4* tB = (const float4*)(target + (size_t)rowB * N_COLS);
        const float4* yA = (const float4*)(y_true + (size_t)rowA * N_COLS);
        const float4* yB = (const float4*)(y_true + (size_t)rowB * N_COLS);

        // issue all 16 coalesced float4 loads up front (named scalars, no arrays)
        float4 ta0 = tA[lane], ta1 = tA[lane + 64], ta2 = tA[lane + 128], ta3 = tA[lane + 192];
        float4 tb0 = tB[lane], tb1 = tB[lane + 64], tb2 = tB[lane + 128], tb3 = tB[lane + 192];
        float4 ya0 = yA[lane], ya1 = yA[lane + 64], ya2 = yA[lane + 128], ya3 = yA[lane + 192];
        float4 yb0 = yB[lane], yb1 = yB[lane + 64], yb2 = yB[lane + 128], yb3 = yB[lane + 192];

        // local argmax, two independent chains; strict > on ascending scan = first-index
        float bvA = -1.0f, bvB = -1.0f;
        int   biA = 0,     biB = 0;
        const int c0 = 4 * lane, c1 = 4 * (lane + 64), c2 = 4 * (lane + 128), c3 = 4 * (lane + 192);
        if (ta0.x > bvA) { bvA = ta0.x; biA = c0;     }
        if (ta0.y > bvA) { bvA = ta0.y; biA = c0 + 1; }
        if (ta0.z > bvA) { bvA = ta0.z; biA = c0 + 2; }
        if (ta0.w > bvA) { bvA = ta0.w; biA = c0 + 3; }
        if (ta1.x > bvA) { bvA = ta1.x; biA = c1;     }
        if (ta1.y > bvA) { bvA = ta1.y; biA = c1 + 1; }
        if (ta1.z > bvA) { bvA = ta1.z; biA = c1 + 2; }
        if (ta1.w > bvA) { bvA = ta1.w; biA = c1 + 3; }
        if (ta2.x > bvA) { bvA = ta2.x; biA = c2;     }
        if (ta2.y > bvA) { bvA = ta2.y; biA = c2 + 1; }
        if (ta2.z > bvA) { bvA = ta2.z; biA = c2 + 2; }
        if (ta2.w > bvA) { bvA = ta2.w; biA = c2 + 3; }
        if (ta3.x > bvA) { bvA = ta3.x; biA = c3;     }
        if (ta3.y > bvA) { bvA = ta3.y; biA = c3 + 1; }
        if (ta3.z > bvA) { bvA = ta3.z; biA = c3 + 2; }
        if (ta3.w > bvA) { bvA = ta3.w; biA = c3 + 3; }
        if (tb0.x > bvB) { bvB = tb0.x; biB = c0;     }
        if (tb0.y > bvB) { bvB = tb0.y; biB = c0 + 1; }
        if (tb0.z > bvB) { bvB = tb0.z; biB = c0 + 2; }
        if (tb0.w > bvB) { bvB = tb0.w; biB = c0 + 3; }
        if (tb1.x > bvB) { bvB = tb1.x; biB = c1;     }
        if (tb1.y > bvB) { bvB = tb1.y; biB = c1 + 1; }
        if (tb1.z > bvB) { bvB = tb1.z; biB = c1 + 2; }
        if (tb1.w > bvB) { bvB = tb1.w; biB = c1 + 3; }
        if (tb2.x > bvB) { bvB = tb2.x; biB = c2;     }
        if (tb2.y > bvB) { bvB = tb2.y; biB = c2 + 1; }
        if (tb2.z > bvB) { bvB = tb2.z; biB = c2 + 2; }
        if (tb2.w > bvB) { bvB = tb2.w; biB = c2 + 3; }
        if (tb3.x > bvB) { bvB = tb3.x; biB = c3;     }
        if (tb3.y > bvB) { bvB = tb3.y; biB = c3 + 1; }
        if (tb3.z > bvB) { bvB = tb3.z; biB = c3 + 2; }
        if (tb3.w > bvB) { bvB = tb3.w; biB = c3 + 3; }

        // cross-lane argmax with first-index tie-break; A and B chains interleave
        #pragma unroll
        for (int m = 32; m >= 1; m >>= 1) {
            float ovA = __shfl_xor(bvA, m, 64); int oiA = __shfl_xor(biA, m, 64);
            if (ovA > bvA || (ovA == bvA && oiA < biA)) { bvA = ovA; biA = oiA; }
            float ovB = __shfl_xor(bvB, m, 64); int oiB = __shfl_xor(biB, m, 64);
            if (ovB > bvB || (ovB == bvB && oiB < biB)) { bvB = ovB; biB = oiB; }
        }
        const int tAi = biA;   // wave-uniform
        const int tBi = biB;

        // weighted sums: lane-private, no per-row reduction (popc(t^t)=0 -> w=0)
        const int xA0 = tAi ^ c0, xA1 = tAi ^ c1, xA2 = tAi ^ c2, xA3 = tAi ^ c3;
        const int xB0 = tBi ^ c0, xB1 = tBi ^ c1, xB2 = tBi ^ c2, xB3 = tBi ^ c3;
        acc_pt += w_lds[__popc(xA0)]     * ya0.x + w_lds[__popc(xA0 ^ 1)] * ya0.y
                + w_lds[__popc(xA0 ^ 2)] * ya0.z + w_lds[__popc(xA0 ^ 3)] * ya0.w
                + w_lds[__popc(xA1)]     * ya1.x + w_lds[__popc(xA1 ^ 1)] * ya1.y
                + w_lds[__popc(xA1 ^ 2)] * ya1.z + w_lds[__popc(xA1 ^ 3)] * ya1.w
                + w_lds[__popc(xA2)]     * ya2.x + w_lds[__popc(xA2 ^ 1)] * ya2.y
                + w_lds[__popc(xA2 ^ 2)] * ya2.z + w_lds[__popc(xA2 ^ 3)] * ya2.w
                + w_lds[__popc(xA3)]     * ya3.x + w_lds[__popc(xA3 ^ 1)] * ya3.y
                + w_lds[__popc(xA3 ^ 2)] * ya3.z + w_lds[__popc(xA3 ^ 3)] * ya3.w
                + w_lds[__popc(xB0)]     * yb0.x + w_lds[__popc(xB0 ^ 1)] * yb0.y
                + w_lds[__popc(xB0 ^ 2)] * yb0.z + w_lds[__popc(xB0 ^ 3)] * yb0.w
                + w_lds[__popc(xB1)]     * yb1.x + w_lds[__popc(xB1 ^ 1)] * yb1.y
                + w_lds[__popc(xB1 ^ 2)] * yb1.z + w_lds[__popc(xB1 ^ 3)] * yb1.w
                + w_lds[__popc(xB2)]     * yb2.x + w_lds[__popc(xB2 ^ 1)] * yb2.y
                + w_lds[__popc(xB2 ^ 2)] * yb2.z + w_lds[__popc(xB2 ^ 3)] * yb2.w
                + w_lds[__popc(xB3)]     * yb3.x + w_lds[__popc(xB3 ^ 1)] * yb3.y
                + w_lds[__popc(xB3 ^ 2)] * yb3.z + w_lds[__popc(xB3 ^ 3)] * yb3.w;

        // CE term: owner lane selects its element with named scalars (no array decay)
        if (((tAi >> 2) & 63) == lane) {
            const int k = tAi >> 8, e = tAi & 3;
            float4 s = (k & 2) ? ((k & 1) ? ya3 : ya2) : ((k & 1) ? ya1 : ya0);
            const float yt = (e & 2) ? ((e & 1) ? s.w : s.z) : ((e & 1) ? s.y : s.x);
            acc_lg += logf(yt + 1e-8f);
        }
        if (((tBi >> 2) & 63) == lane) {
            const int k = tBi >> 8, e = tBi & 3;
            float4 s = (k & 2) ? ((k & 1) ? yb3 : yb2) : ((k & 1) ? yb1 : yb0);
            const float yt = (e & 2) ? ((e & 1) ? s.w : s.z) : ((e & 1) ? s.y : s.x);
            acc_lg += logf(yt + 1e-8f);
        }
    }

    // single per-wave reduction at the end
    const float invB  = 1.0f / (float)B_ROWS;
    const float invBN = 1.0f / ((float)B_ROWS * (float)N_COLS);
    float val = acc_pt * invBN - acc_lg * invB;
    #pragma unroll
    for (int m = 32; m >= 1; m >>= 1) val += __shfl_xor(val, m, 64);

    if (lane == 0) wave_part[wid] = val;
    __syncthreads();
    if (tid == 0) {
        float s = 0.0f;
        #pragma unroll
        for (int w = 0; w < WAVES_PER_BLOCK; ++w) s += wave_part[w];
        atomicAdd(out, s);   // 2048 adds; reorder noise ~1e-3 << threshold 2764
    }
}

extern "C" void kernel_launch(void* const* d_in, const int* in_sizes, int n_in,
                              void* d_out, int out_size, void* d_ws, size_t ws_size,
                              hipStream_t stream) {
    const float* y_true = (const float*)d_in[0];
    const float* target = (const float*)d_in[1];
    float* out = (float*)d_out;

    hipMemsetAsync(out, 0, sizeof(float), stream);
    ce_rows_kernel<<<ROWS_BLOCKS, ROWS_THREADS, 0, stream>>>(y_true, target, out);
}

// Round 12
// 102.976 us; speedup vs baseline: 1.3817x; 1.3817x over previous
//
#include <hip/hip_runtime.h>
#include <math.h>

// B=65536 rows, N=1024 cols, fp32.
//   t_b = argmax_c target[b,c]  (first-max tie-break)
//   out = mean_b(-log(y[b,t_b]+1e-8)) + sum_{b,c} w[popc(t_b^c)]*y[b,c]/(B*N),  w[p]=(p==0)?0:6^p
// CHAMPION (R4, 99.6us): 2-row interleave, by-value helper formulation. R10/R11 lesson:
// manually inlining these helpers flips codegen into LDS-spill (19.5KB LDS, 104MB scratch
// writes, 142us). The helper-function source shape is LOAD-BEARING. Do not inline.

#define B_ROWS 65536
#define N_COLS 1024
#define WAVES_PER_BLOCK 4
#define ROWS_BLOCKS 2048
#define ROWS_THREADS (WAVES_PER_BLOCK * 64)
#define NWAVES (ROWS_BLOCKS * WAVES_PER_BLOCK)  // 8192 -> 8 rows/wave, 4 ILP2-iters

__device__ __forceinline__ void amax4(float4 v, int c0, float& bv, int& bi) {
    // ascending-column scan within the lane: strict > gives first-index semantics
    if (v.x > bv) { bv = v.x; bi = c0;     }
    if (v.y > bv) { bv = v.y; bi = c0 + 1; }
    if (v.z > bv) { bv = v.z; bi = c0 + 2; }
    if (v.w > bv) { bv = v.w; bi = c0 + 3; }
}

__device__ __forceinline__ float wsum4(const float* w_lds, float4 v, int x) {
    // x = t ^ c0 with c0 % 4 == 0, so t^(c0+e) = x^e
    return w_lds[__popc(x)]     * v.x + w_lds[__popc(x ^ 1)] * v.y +
           w_lds[__popc(x ^ 2)] * v.z + w_lds[__popc(x ^ 3)] * v.w;
}

__device__ __forceinline__ float pick16(float4 v0, float4 v1, float4 v2, float4 v3, int t) {
    // statically-indexed select of element (t>>6 -> which float4 within lane, t&3 -> component)
    const int k = (t >> 2) >> 6;   // 0..3
    const int e = t & 3;
    float4 s = (k & 2) ? ((k & 1) ? v3 : v2) : ((k & 1) ? v1 : v0);
    return (e & 2) ? ((e & 1) ? s.w : s.z) : ((e & 1) ? s.y : s.x);
}

__global__ __launch_bounds__(ROWS_THREADS)
void ce_rows_kernel(const float* __restrict__ y_true,
                    const float* __restrict__ target,
                    float* __restrict__ partials) {
    __shared__ float w_lds[16];
    __shared__ float wave_part[WAVES_PER_BLOCK];

    const int tid = threadIdx.x;
    if (tid < 16) {
        float w = 1.0f;
        for (int p = 0; p < tid; ++p) w *= 6.0f;   // exact: 6^10 < 2^26
        w_lds[tid] = (tid == 0) ? 0.0f : w;
    }
    __syncthreads();

    const int lane  = tid & 63;
    const int wid   = tid >> 6;
    const int gwave = blockIdx.x * WAVES_PER_BLOCK + wid;

    float acc_pt = 0.0f;   // lane-private weighted-sum partial (unscaled)
    float acc_lg = 0.0f;   // lane-private sum of log(y[t]+1e-8) (owner lanes only)

    for (int base = gwave; base < B_ROWS; base += 2 * NWAVES) {
        const int rowA = base;
        const int rowB = base + NWAVES;
        const float4* tA = (const float4*)(target + (size_t)rowA * N_COLS);
        const float4* tB = (const float4*)(target + (size_t)rowB * N_COLS);
        const float4* yA = (const float4*)(y_true + (size_t)rowA * N_COLS);
        const float4* yB = (const float4*)(y_true + (size_t)rowB * N_COLS);

        // issue all 16 coalesced float4 loads up front (addresses independent of t)
        float4 ta0 = tA[lane], ta1 = tA[lane + 64], ta2 = tA[lane + 128], ta3 = tA[lane + 192];
        float4 tb0 = tB[lane], tb1 = tB[lane + 64], tb2 = tB[lane + 128], tb3 = tB[lane + 192];
        float4 ya0 = yA[lane], ya1 = yA[lane + 64], ya2 = yA[lane + 128], ya3 = yA[lane + 192];
        float4 yb0 = yB[lane], yb1 = yB[lane + 64], yb2 = yB[lane + 128], yb3 = yB[lane + 192];

        // local argmax, two independent chains (inputs uniform [0,1) => > -1)
        float bvA = -1.0f, bvB = -1.0f;
        int   biA = 0,     biB = 0;
        amax4(ta0, 4 * lane,         bvA, biA);
        amax4(ta1, 4 * (lane + 64),  bvA, biA);
        amax4(ta2, 4 * (lane + 128), bvA, biA);
        amax4(ta3, 4 * (lane + 192), bvA, biA);
        amax4(tb0, 4 * lane,         bvB, biB);
        amax4(tb1, 4 * (lane + 64),  bvB, biB);
        amax4(tb2, 4 * (lane + 128), bvB, biB);
        amax4(tb3, 4 * (lane + 192), bvB, biB);

        // cross-lane argmax with first-index tie-break; A and B chains overlap
        #pragma unroll
        for (int m = 32; m >= 1; m >>= 1) {
            float ovA = __shfl_xor(bvA, m, 64); int oiA = __shfl_xor(biA, m, 64);
            if (ovA > bvA || (ovA == bvA && oiA < biA)) { bvA = ovA; biA = oiA; }
            float ovB = __shfl_xor(bvB, m, 64); int oiB = __shfl_xor(biB, m, 64);
            if (ovB > bvB || (ovB == bvB && oiB < biB)) { bvB = ovB; biB = oiB; }
        }
        const int tAi = biA;   // wave-uniform
        const int tBi = biB;

        // weighted sums: lane-private accumulation, NO per-row reduction.
        // popc(t^t)=0 -> w=0 excludes the target class automatically.
        acc_pt += wsum4(w_lds, ya0, tAi ^ (4 * lane))
                + wsum4(w_lds, ya1, tAi ^ (4 * (lane + 64)))
                + wsum4(w_lds, ya2, tAi ^ (4 * (lane + 128)))
                + wsum4(w_lds, ya3, tAi ^ (4 * (lane + 192)))
                + wsum4(w_lds, yb0, tBi ^ (4 * lane))
                + wsum4(w_lds, yb1, tBi ^ (4 * (lane + 64)))
                + wsum4(w_lds, yb2, tBi ^ (4 * (lane + 128)))
                + wsum4(w_lds, yb3, tBi ^ (4 * (lane + 192)));

        // CE term: only the lane owning column t computes the log (no shuffle chain)
        if (((tAi >> 2) & 63) == lane)
            acc_lg += logf(pick16(ya0, ya1, ya2, ya3, tAi) + 1e-8f);
        if (((tBi >> 2) & 63) == lane)
            acc_lg += logf(pick16(yb0, yb1, yb2, yb3, tBi) + 1e-8f);
    }

    // single per-wave reduction at the end
    const float invB  = 1.0f / (float)B_ROWS;
    const float invBN = 1.0f / ((float)B_ROWS * (float)N_COLS);
    float val = acc_pt * invBN - acc_lg * invB;
    #pragma unroll
    for (int m = 32; m >= 1; m >>= 1) val += __shfl_xor(val, m, 64);

    if (lane == 0) wave_part[wid] = val;
    __syncthreads();
    if (tid == 0) {
        float s = 0.0f;
        #pragma unroll
        for (int w = 0; w < WAVES_PER_BLOCK; ++w) s += wave_part[w];
        partials[blockIdx.x] = s;
    }
}

__global__ __launch_bounds__(256)
void ce_reduce_kernel(const float* __restrict__ partials, int n, float* __restrict__ out) {
    __shared__ float s[256];
    const int tid = threadIdx.x;
    float a = 0.0f;
    for (int i = tid; i < n; i += 256) a += partials[i];  // fixed order -> deterministic
    s[tid] = a;
    __syncthreads();
    for (int off = 128; off > 0; off >>= 1) {
        if (tid < off) s[tid] += s[tid + off];
        __syncthreads();
    }
    if (tid == 0) out[0] = s[0];
}

extern "C" void kernel_launch(void* const* d_in, const int* in_sizes, int n_in,
                              void* d_out, int out_size, void* d_ws, size_t ws_size,
                              hipStream_t stream) {
    const float* y_true = (const float*)d_in[0];
    const float* target = (const float*)d_in[1];
    float* out = (float*)d_out;
    float* partials = (float*)d_ws;  // ROWS_BLOCKS floats = 8 KB

    ce_rows_kernel<<<ROWS_BLOCKS, ROWS_THREADS, 0, stream>>>(y_true, target, partials);
    ce_reduce_kernel<<<1, 256, 0, stream>>>(partials, ROWS_BLOCKS, out);
}

// Round 13
// 97.212 us; speedup vs baseline: 1.4637x; 1.0593x over previous
//
#include <hip/hip_runtime.h>
#include <math.h>

// B=65536 rows, N=1024 cols, fp32.
//   t_b = argmax_c target[b,c]  (first-max tie-break)
//   out = mean_b(-log(y[b,t_b]+1e-8)) + sum_{b,c} w[popc(t_b^c)]*y[b,c]/(B*N),  w[p]=(p==0)?0:6^p
// R13: single-row loop, target row double-buffered in REGISTERS one iter ahead.
// Working set 12 float4 (< R4's 16): amax waits on nothing (t resident), chain hides
// y + t-next loads. Exact R4 helper formulation (load-bearing vs LDS-promote, R10/R11).

#define B_ROWS 65536
#define N_COLS 1024
#define WAVES_PER_BLOCK 4
#define ROWS_BLOCKS 2048
#define ROWS_THREADS (WAVES_PER_BLOCK * 64)
#define NWAVES (ROWS_BLOCKS * WAVES_PER_BLOCK)  // 8192 waves -> 8 rows/wave
#define ROWS_PER_WAVE 8

__device__ __forceinline__ void amax4(float4 v, int c0, float& bv, int& bi) {
    // ascending-column scan within the lane: strict > gives first-index semantics
    if (v.x > bv) { bv = v.x; bi = c0;     }
    if (v.y > bv) { bv = v.y; bi = c0 + 1; }
    if (v.z > bv) { bv = v.z; bi = c0 + 2; }
    if (v.w > bv) { bv = v.w; bi = c0 + 3; }
}

__device__ __forceinline__ float wsum4(const float* w_lds, float4 v, int x) {
    // x = t ^ c0 with c0 % 4 == 0, so t^(c0+e) = x^e
    return w_lds[__popc(x)]     * v.x + w_lds[__popc(x ^ 1)] * v.y +
           w_lds[__popc(x ^ 2)] * v.z + w_lds[__popc(x ^ 3)] * v.w;
}

__device__ __forceinline__ float pick16(float4 v0, float4 v1, float4 v2, float4 v3, int t) {
    // statically-indexed select (t>>8 -> which float4 within owning lane, t&3 -> component)
    const int k = (t >> 2) >> 6;   // 0..3
    const int e = t & 3;
    float4 s = (k & 2) ? ((k & 1) ? v3 : v2) : ((k & 1) ? v1 : v0);
    return (e & 2) ? ((e & 1) ? s.w : s.z) : ((e & 1) ? s.y : s.x);
}

__global__ __launch_bounds__(ROWS_THREADS)
void ce_rows_kernel(const float* __restrict__ y_true,
                    const float* __restrict__ target,
                    float* __restrict__ partials) {
    __shared__ float w_lds[16];
    __shared__ float wave_part[WAVES_PER_BLOCK];

    const int tid = threadIdx.x;
    if (tid < 16) {
        float w = 1.0f;
        for (int p = 0; p < tid; ++p) w *= 6.0f;   // exact: 6^10 < 2^26
        w_lds[tid] = (tid == 0) ? 0.0f : w;
    }
    __syncthreads();

    const int lane  = tid & 63;
    const int wid   = tid >> 6;
    const int gwave = blockIdx.x * WAVES_PER_BLOCK + wid;

    float acc_pt = 0.0f;   // lane-private weighted-sum partial (unscaled)
    float acc_lg = 0.0f;   // lane-private sum of log(y[t]+1e-8) (owner lanes only)

    // prologue: target row for s=0 into the current buffer
    const float4* tp0 = (const float4*)(target + (size_t)gwave * N_COLS);
    float4 tc0 = tp0[lane], tc1 = tp0[lane + 64], tc2 = tp0[lane + 128], tc3 = tp0[lane + 192];

    #pragma unroll 1
    for (int s = 0; s < ROWS_PER_WAVE; ++s) {
        const int row = gwave + s * NWAVES;

        // issue y(row) loads — consumed only after the chain (latency hidden)
        const float4* yp = (const float4*)(y_true + (size_t)row * N_COLS);
        float4 y0 = yp[lane], y1 = yp[lane + 64], y2 = yp[lane + 128], y3 = yp[lane + 192];

        // issue t(row+NWAVES) prefetch — consumed next iteration (fully hidden)
        float4 tn0 = tc0, tn1 = tc1, tn2 = tc2, tn3 = tc3;
        if (s < ROWS_PER_WAVE - 1) {   // wave-uniform branch
            const float4* tn = (const float4*)(target + (size_t)(row + NWAVES) * N_COLS);
            tn0 = tn[lane]; tn1 = tn[lane + 64]; tn2 = tn[lane + 128]; tn3 = tn[lane + 192];
        }

        // local argmax on resident t (no memory wait); strict > = first-index
        float bv = -1.0f; int bi = 0;
        amax4(tc0, 4 * lane,         bv, bi);
        amax4(tc1, 4 * (lane + 64),  bv, bi);
        amax4(tc2, 4 * (lane + 128), bv, bi);
        amax4(tc3, 4 * (lane + 192), bv, bi);

        // cross-lane argmax with first-index tie-break; y/t-next stream in underneath
        #pragma unroll
        for (int m = 32; m >= 1; m >>= 1) {
            const float ov = __shfl_xor(bv, m, 64);
            const int   oi = __shfl_xor(bi, m, 64);
            if (ov > bv || (ov == bv && oi < bi)) { bv = ov; bi = oi; }
        }
        const int t = bi;   // wave-uniform

        // weighted sum: lane-private, no per-row reduction (popc(t^t)=0 -> w=0)
        acc_pt += wsum4(w_lds, y0, t ^ (4 * lane))
                + wsum4(w_lds, y1, t ^ (4 * (lane + 64)))
                + wsum4(w_lds, y2, t ^ (4 * (lane + 128)))
                + wsum4(w_lds, y3, t ^ (4 * (lane + 192)));

        // CE term: only the lane owning column t computes the log
        if (((t >> 2) & 63) == lane)
            acc_lg += logf(pick16(y0, y1, y2, y3, t) + 1e-8f);

        // rotate the double buffer
        tc0 = tn0; tc1 = tn1; tc2 = tn2; tc3 = tn3;
    }

    // single per-wave reduction at the end
    const float invB  = 1.0f / (float)B_ROWS;
    const float invBN = 1.0f / ((float)B_ROWS * (float)N_COLS);
    float val = acc_pt * invBN - acc_lg * invB;
    #pragma unroll
    for (int m = 32; m >= 1; m >>= 1) val += __shfl_xor(val, m, 64);

    if (lane == 0) wave_part[wid] = val;
    __syncthreads();
    if (tid == 0) {
        float s = 0.0f;
        #pragma unroll
        for (int w = 0; w < WAVES_PER_BLOCK; ++w) s += wave_part[w];
        partials[blockIdx.x] = s;
    }
}

__global__ __launch_bounds__(256)
void ce_reduce_kernel(const float* __restrict__ partials, int n, float* __restrict__ out) {
    __shared__ float s[256];
    const int tid = threadIdx.x;
    float a = 0.0f;
    for (int i = tid; i < n; i += 256) a += partials[i];  // fixed order -> deterministic
    s[tid] = a;
    __syncthreads();
    for (int off = 128; off > 0; off >>= 1) {
        if (tid < off) s[tid] += s[tid + off];
        __syncthreads();
    }
    if (tid == 0) out[0] = s[0];
}

extern "C" void kernel_launch(void* const* d_in, const int* in_sizes, int n_in,
                              void* d_out, int out_size, void* d_ws, size_t ws_size,
                              hipStream_t stream) {
    const float* y_true = (const float*)d_in[0];
    const float* target = (const float*)d_in[1];
    float* out = (float*)d_out;
    float* partials = (float*)d_ws;  // ROWS_BLOCKS floats = 8 KB

    ce_rows_kernel<<<ROWS_BLOCKS, ROWS_THREADS, 0, stream>>>(y_true, target, partials);
    ce_reduce_kernel<<<1, 256, 0, stream>>>(partials, ROWS_BLOCKS, out);
}